// Round 21
// baseline (97.060 us; speedup 1.0000x reference)
//
#include <hip/hip_runtime.h>
#include <hip/hip_bf16.h>

#define N_SIDE 14
#define N_PATCH (N_SIDE * N_SIDE)   // 196
#define D_BB 384
#define DQ_BB (D_BB / 4)             // 96 float4 per cell
#define D_MODEL 512
#define BT_TOTAL 2048
#define LN_EPS 1e-5f
#define PGROUPS 8                    // pool cell groups (768 threads)
#define KSTEPS (D_BB / 32)           // 12 MFMA K-steps
#define NGEMM (BT_TOTAL / 16)        // 128 gemm blocks

typedef __attribute__((ext_vector_type(8))) short bf16x8;
typedef __attribute__((ext_vector_type(4))) float f32x4;

__device__ __forceinline__ unsigned short f2b(float f) {
    unsigned u = __float_as_uint(f);
    return (unsigned short)((u + 0x7FFFu + ((u >> 16) & 1u)) >> 16);
}

__device__ __forceinline__ void add4(float4& a, const float4& b) {
    a.x += b.x; a.y += b.y; a.z += b.z; a.w += b.w;
}

__device__ __forceinline__ void box_params(const float* __restrict__ bboxes, int bt,
                                           int& x1, int& y1, int& wd, int& total) {
    const float bx1 = bboxes[bt * 4 + 0];
    const float by1 = bboxes[bt * 4 + 1];
    const float bx2 = bboxes[bt * 4 + 2];
    const float by2 = bboxes[bt * 4 + 3];
    // match reference exactly: clip -> trunc/ceil -> clip -> max
    x1 = (int)fminf(fmaxf(bx1 * (float)N_SIDE, 0.f), (float)(N_SIDE - 1));
    y1 = (int)fminf(fmaxf(by1 * (float)N_SIDE, 0.f), (float)(N_SIDE - 1));
    int x2 = (int)fminf(fmaxf(ceilf(fminf(fmaxf(bx2 * (float)N_SIDE, 0.f), (float)N_SIDE)), 1.f), (float)N_SIDE);
    int y2 = (int)fminf(fmaxf(ceilf(fminf(fmaxf(by2 * (float)N_SIDE, 0.f), (float)N_SIDE)), 1.f), (float)N_SIDE);
    x2 = max(x2, x1 + 1);
    y2 = max(y2, y1 + 1);
    wd = x2 - x1;
    total = wd * (y2 - y1);
}

// ---------------- Single dispatch: 2048 pool blocks + 128 gemm blocks ----------------
// flags[0] = wpack counter (64 when done); flags[1+g] = rows pooled for tile g (16 when ready).
// Pool role = R16 pool verbatim + release-flag. Gemm role = R16 MFMA verbatim + acquire-spin.
__global__ __launch_bounds__(768) void fused_all(
    const float* __restrict__ patch,     // [BT,196,384]
    const float* __restrict__ bboxes,    // [BT,4]
    const float* __restrict__ W,         // [384,512]
    int*         __restrict__ flags,     // [1+128], pre-zeroed
    unsigned short* __restrict__ pooled_bf, // [BT,384]
    unsigned short* __restrict__ wpack,  // [32][12][64][8]
    const float* __restrict__ bias,      // [512]
    const float* __restrict__ gamma,     // [512]
    const float* __restrict__ beta,      // [512]
    const float* __restrict__ mask_tok,  // [512]
    const float* __restrict__ vis,       // [BT]
    float* __restrict__ out)             // [BT,512]
{
    const int bid = blockIdx.x;
    const int tid = threadIdx.x;

    if (bid < BT_TOTAL) {
        // ======================= POOL ROLE (R16 verbatim) =======================
        const int bt = bid;
        const int t  = tid;
        const int qd = t % DQ_BB;   // channel quad 0..95
        const int g  = t / DQ_BB;   // cell group 0..7

        // ---- W pack (first 64 blocks) ----
        if (bt < 64) {
            const int nt   = bt >> 1;
            const int kh   = bt & 1;
            const int lane = t & 63;
            const int grp  = t >> 6;           // 0..11
            const int ksl  = grp >> 1;
            const int jh   = grp & 1;
            const int ks   = kh * 6 + ksl;
            const int n    = nt * 16 + (lane & 15);
            const int kb   = ks * 32 + (lane >> 4) * 8 + jh * 4;
            ushort4 w4;
            w4.x = f2b(W[(size_t)(kb + 0) * D_MODEL + n]);
            w4.y = f2b(W[(size_t)(kb + 1) * D_MODEL + n]);
            w4.z = f2b(W[(size_t)(kb + 2) * D_MODEL + n]);
            w4.w = f2b(W[(size_t)(kb + 3) * D_MODEL + n]);
            *(ushort4*)(wpack + ((size_t)(nt * KSTEPS + ks) * 64 + lane) * 8 + jh * 4) = w4;
        }

        int x1, y1, wd, total;
        box_params(bboxes, bt, x1, y1, wd, total);
        const float inv_count = 1.f / (float)total;
        const float inv_wd = 1.f / (float)wd;
        const int cell0 = y1 * N_SIDE + x1;

        const float4* __restrict__ base =
            (const float4*)patch + (size_t)bt * N_PATCH * DQ_BB + qd;

        auto cell_off = [&](int c) -> size_t {
            const int y = (int)(((float)c + 0.5f) * inv_wd);
            const int x = c - y * wd;
            return (size_t)(cell0 + y * N_SIDE + x) * DQ_BB;
        };

        float4 acc = make_float4(0.f, 0.f, 0.f, 0.f);
        int c = g;
        for (; c + 3 * PGROUPS < total; c += 4 * PGROUPS) {
            const float4 v0 = base[cell_off(c)];
            const float4 v1 = base[cell_off(c + PGROUPS)];
            const float4 v2 = base[cell_off(c + 2 * PGROUPS)];
            const float4 v3 = base[cell_off(c + 3 * PGROUPS)];
            acc.x += (v0.x + v1.x) + (v2.x + v3.x);
            acc.y += (v0.y + v1.y) + (v2.y + v3.y);
            acc.z += (v0.z + v1.z) + (v2.z + v3.z);
            acc.w += (v0.w + v1.w) + (v2.w + v3.w);
        }
        for (; c < total; c += PGROUPS) {
            const float4 v = base[cell_off(c)];
            acc.x += v.x; acc.y += v.y; acc.z += v.z; acc.w += v.w;
        }

        __shared__ float4 part[PGROUPS][DQ_BB];   // 12 KB
        part[g][qd] = acc;
        __syncthreads();

        if (t < DQ_BB) {
            float4 s = part[0][t];
#pragma unroll
            for (int p = 1; p < PGROUPS; ++p) add4(s, part[p][t]);
            ushort4 o;
            o.x = f2b(s.x * inv_count);
            o.y = f2b(s.y * inv_count);
            o.z = f2b(s.z * inv_count);
            o.w = f2b(s.w * inv_count);
            *(ushort4*)(pooled_bf + (size_t)bt * D_BB + t * 4) = o;
        }
        __syncthreads();   // all stores issued (waitcnt before barrier)

        if (t == 0) {
            // device-scope release: publishes pooled row (and wpack slice) across XCDs
            __hip_atomic_fetch_add(&flags[1 + (bt >> 4)], 1,
                                   __ATOMIC_RELEASE, __HIP_MEMORY_SCOPE_AGENT);
            if (bt < 64)
                __hip_atomic_fetch_add(&flags[0], 1,
                                       __ATOMIC_RELEASE, __HIP_MEMORY_SCOPE_AGENT);
        }
        return;
    }

    // ======================= GEMM ROLE (R16 MFMA verbatim) =======================
    const int gblk  = bid - BT_TOTAL;    // 0..127
    const int mrow0 = gblk * 16;

    if (tid == 0) {
        while (__hip_atomic_load(&flags[0], __ATOMIC_ACQUIRE,
                                 __HIP_MEMORY_SCOPE_AGENT) < 64)
            __builtin_amdgcn_s_sleep(2);
        while (__hip_atomic_load(&flags[1 + gblk], __ATOMIC_ACQUIRE,
                                 __HIP_MEMORY_SCOPE_AGENT) < 16)
            __builtin_amdgcn_s_sleep(2);
    }
    __syncthreads();

    __shared__ float lns[8][16][2];   // [ch][m][{s,s2}], 1 KB

    const int ch     = tid >> 6;          // col-eighth 0..7 (4 n-tiles each)
    const int lane   = tid & 63;
    const int lane_m = lane & 15;
    const int lane_g = lane >> 4;

    f32x4 acc[4];
    float s[4] = {0.f, 0.f, 0.f, 0.f}, s2[4] = {0.f, 0.f, 0.f, 0.f};

    if (tid < 512) {
        bf16x8 afrag[KSTEPS];
        {
            const unsigned short* Arow =
                pooled_bf + (size_t)(mrow0 + lane_m) * D_BB + lane_g * 8;
#pragma unroll
            for (int ks = 0; ks < KSTEPS; ++ks)
                afrag[ks] = *(const bf16x8*)(Arow + ks * 32);
        }

#pragma unroll
        for (int nt = 0; nt < 4; ++nt) acc[nt] = (f32x4){0.f, 0.f, 0.f, 0.f};

#pragma unroll
        for (int nt = 0; nt < 4; ++nt) {
            const unsigned short* bp =
                wpack + ((size_t)((ch * 4 + nt) * KSTEPS) * 64 + lane) * 8;
#pragma unroll
            for (int ks = 0; ks < KSTEPS; ++ks) {
                const bf16x8 b = *(const bf16x8*)(bp + (size_t)ks * 64 * 8);
                acc[nt] = __builtin_amdgcn_mfma_f32_16x16x32_bf16(afrag[ks], b, acc[nt], 0, 0, 0);
            }
        }

#pragma unroll
        for (int nt = 0; nt < 4; ++nt) {
            const float bs = bias[ch * 64 + nt * 16 + lane_m];
#pragma unroll
            for (int r = 0; r < 4; ++r) {
                const float v = acc[nt][r] + bs;
                acc[nt][r] = v;
                s[r] += v; s2[r] += v * v;
            }
        }
#pragma unroll
        for (int off = 1; off < 16; off <<= 1) {
#pragma unroll
            for (int r = 0; r < 4; ++r) {
                s[r]  += __shfl_xor(s[r],  off);
                s2[r] += __shfl_xor(s2[r], off);
            }
        }
        if (lane_m == 0) {
#pragma unroll
            for (int r = 0; r < 4; ++r) {
                lns[ch][lane_g * 4 + r][0] = s[r];
                lns[ch][lane_g * 4 + r][1] = s2[r];
            }
        }
    }
    __syncthreads();

    if (tid < 512) {
        float mean4[4], rstd4[4], v4[4], iv4[4];
#pragma unroll
        for (int r = 0; r < 4; ++r) {
            const int m = lane_g * 4 + r;
            float S = 0.f, S2 = 0.f;
#pragma unroll
            for (int cc = 0; cc < 8; ++cc) { S += lns[cc][m][0]; S2 += lns[cc][m][1]; }
            const float mean = S * (1.f / (float)D_MODEL);
            const float var  = S2 * (1.f / (float)D_MODEL) - mean * mean;
            mean4[r] = mean;
            rstd4[r] = rsqrtf(var + LN_EPS);
            const float v = vis[mrow0 + m];
            v4[r] = v; iv4[r] = 1.f - v;
        }

#pragma unroll
        for (int nt = 0; nt < 4; ++nt) {
            const int n = ch * 64 + nt * 16 + lane_m;
            const float gm  = gamma[n];
            const float bt_ = beta[n];
            const float mt  = mask_tok[n];
#pragma unroll
            for (int r = 0; r < 4; ++r) {
                const int row = mrow0 + lane_g * 4 + r;
                const float o = v4[r] * ((acc[nt][r] - mean4[r]) * rstd4[r] * gm + bt_) + iv4[r] * mt;
                out[(size_t)row * D_MODEL + n] = o;
            }
        }
    }
}

extern "C" void kernel_launch(void* const* d_in, const int* in_sizes, int n_in,
                              void* d_out, int out_size, void* d_ws, size_t ws_size,
                              hipStream_t stream) {
    const float* patch  = (const float*)d_in[0];  // [2048,196,384]
    const float* bboxes = (const float*)d_in[1];  // [2048,4]
    const float* vis    = (const float*)d_in[2];  // [2048]
    // d_in[3] = B, d_in[4] = T (scalars, unused)
    const float* W      = (const float*)d_in[5];  // [384,512]
    const float* bias   = (const float*)d_in[6];  // [512]
    const float* gamma  = (const float*)d_in[7];  // [512]
    const float* beta   = (const float*)d_in[8];  // [512]
    const float* mtok   = (const float*)d_in[9];  // [1,512]

    int*            flags     = (int*)d_ws;                                  // 1 KB
    unsigned short* pooled_bf = (unsigned short*)((char*)d_ws + (1u << 20)); // 1.5 MB
    unsigned short* wpack     = (unsigned short*)((char*)d_ws + (3u << 20)); // 384 KB
    float* out = (float*)d_out;

    hipMemsetAsync(flags, 0, 1024, stream);
    fused_all<<<BT_TOTAL + NGEMM, 768, 0, stream>>>(
        patch, bboxes, W, flags, pooled_bf, wpack,
        bias, gamma, beta, mtok, vis, out);
}

// Round 22
// 32.049 us; speedup vs baseline: 3.0285x; 3.0285x over previous
//
#include <hip/hip_runtime.h>
#include <hip/hip_bf16.h>

#define N_SIDE 14
#define N_PATCH (N_SIDE * N_SIDE)   // 196
#define D_BB 384
#define DQ_BB (D_BB / 4)             // 96 float4 per cell
#define D_MODEL 512
#define BT_TOTAL 2048
#define LN_EPS 1e-5f
#define PGROUPS 8                    // pool cell groups (768 threads)
#define KSTEPS (D_BB / 32)           // 12 MFMA K-steps

typedef __attribute__((ext_vector_type(8))) short bf16x8;
typedef __attribute__((ext_vector_type(4))) float f32x4;

__device__ __forceinline__ unsigned short f2b(float f) {
    // RNE float -> bf16 (finite data)
    unsigned u = __float_as_uint(f);
    return (unsigned short)((u + 0x7FFFu + ((u >> 16) & 1u)) >> 16);
}

__device__ __forceinline__ void add4(float4& a, const float4& b) {
    a.x += b.x; a.y += b.y; a.z += b.z; a.w += b.w;
}

__device__ __forceinline__ void box_params(const float* __restrict__ bboxes, int bt,
                                           int& x1, int& y1, int& wd, int& total) {
    const float bx1 = bboxes[bt * 4 + 0];
    const float by1 = bboxes[bt * 4 + 1];
    const float bx2 = bboxes[bt * 4 + 2];
    const float by2 = bboxes[bt * 4 + 3];
    // match reference exactly: clip -> trunc/ceil -> clip -> max
    x1 = (int)fminf(fmaxf(bx1 * (float)N_SIDE, 0.f), (float)(N_SIDE - 1));
    y1 = (int)fminf(fmaxf(by1 * (float)N_SIDE, 0.f), (float)(N_SIDE - 1));
    int x2 = (int)fminf(fmaxf(ceilf(fminf(fmaxf(bx2 * (float)N_SIDE, 0.f), (float)N_SIDE)), 1.f), (float)N_SIDE);
    int y2 = (int)fminf(fmaxf(ceilf(fminf(fmaxf(by2 * (float)N_SIDE, 0.f), (float)N_SIDE)), 1.f), (float)N_SIDE);
    x2 = max(x2, x1 + 1);
    y2 = max(y2, y1 + 1);
    wd = x2 - x1;
    total = wd * (y2 - y1);
}

// ---------------- Kernel 1: ROI mean pool -> bf16, + W pack (blocks 0..63) ----------------
__global__ __launch_bounds__(768) void pool_kernel(
    const float* __restrict__ patch,   // [BT,196,384]
    const float* __restrict__ bboxes,  // [BT,4]
    const float* __restrict__ W,       // [384,512]
    unsigned short* __restrict__ pooled_bf, // [BT,384] bf16 means
    unsigned short* __restrict__ wpack)     // [32][12][64][8] bf16 B-fragments
{
    const int bt = blockIdx.x;
    const int t  = threadIdx.x;
    const int qd = t % DQ_BB;   // channel quad 0..95
    const int g  = t / DQ_BB;   // cell group 0..7

    // ---- W pack (first 64 blocks; independent of pooling) ----
    if (bt < 64) {
        const int nt   = bt >> 1;          // n-tile 0..31
        const int kh   = bt & 1;           // k-step half
        const int lane = t & 63;
        const int grp  = t >> 6;           // 0..11
        const int ksl  = grp >> 1;         // 0..5
        const int jh   = grp & 1;          // j half
        const int ks   = kh * 6 + ksl;     // k-step 0..11
        const int n    = nt * 16 + (lane & 15);
        const int kb   = ks * 32 + (lane >> 4) * 8 + jh * 4;
        ushort4 w4;
        w4.x = f2b(W[(size_t)(kb + 0) * D_MODEL + n]);
        w4.y = f2b(W[(size_t)(kb + 1) * D_MODEL + n]);
        w4.z = f2b(W[(size_t)(kb + 2) * D_MODEL + n]);
        w4.w = f2b(W[(size_t)(kb + 3) * D_MODEL + n]);
        *(ushort4*)(wpack + ((size_t)(nt * KSTEPS + ks) * 64 + lane) * 8 + jh * 4) = w4;
    }

    int x1, y1, wd, total;
    box_params(bboxes, bt, x1, y1, wd, total);
    const float inv_count = 1.f / (float)total;
    const float inv_wd = 1.f / (float)wd;
    const int cell0 = y1 * N_SIDE + x1;

    const float4* __restrict__ base = (const float4*)patch + (size_t)bt * N_PATCH * DQ_BB + qd;

    auto cell_off = [&](int c) -> size_t {
        const int y = (int)(((float)c + 0.5f) * inv_wd);
        const int x = c - y * wd;
        return (size_t)(cell0 + y * N_SIDE + x) * DQ_BB;
    };

    float4 acc = make_float4(0.f, 0.f, 0.f, 0.f);
    int c = g;
    for (; c + 3 * PGROUPS < total; c += 4 * PGROUPS) {
        const float4 v0 = base[cell_off(c)];
        const float4 v1 = base[cell_off(c + PGROUPS)];
        const float4 v2 = base[cell_off(c + 2 * PGROUPS)];
        const float4 v3 = base[cell_off(c + 3 * PGROUPS)];
        acc.x += (v0.x + v1.x) + (v2.x + v3.x);
        acc.y += (v0.y + v1.y) + (v2.y + v3.y);
        acc.z += (v0.z + v1.z) + (v2.z + v3.z);
        acc.w += (v0.w + v1.w) + (v2.w + v3.w);
    }
    for (; c < total; c += PGROUPS) {
        const float4 v = base[cell_off(c)];
        acc.x += v.x; acc.y += v.y; acc.z += v.z; acc.w += v.w;
    }

    __shared__ float4 part[PGROUPS][DQ_BB];   // 12 KB
    part[g][qd] = acc;
    __syncthreads();

    if (t < DQ_BB) {
        float4 s = part[0][t];
#pragma unroll
        for (int p = 1; p < PGROUPS; ++p) add4(s, part[p][t]);
        ushort4 o;
        o.x = f2b(s.x * inv_count);
        o.y = f2b(s.y * inv_count);
        o.z = f2b(s.z * inv_count);
        o.w = f2b(s.w * inv_count);
        *(ushort4*)(pooled_bf + (size_t)bt * D_BB + t * 4) = o;
    }
}

// ---------------- Kernel 2: MFMA bf16 GEMM, 512 thr = 8 waves (2/SIMD) ----------------
// grid = 128 blocks x 512 thr. Block: 16 rows x 512 cols. Wave = 4 n-tiles (64 cols).
__global__ __launch_bounds__(512) void mfma_ln_kernel(
    const unsigned short* __restrict__ pooled_bf, // [BT,384] bf16
    const unsigned short* __restrict__ wpack,     // [32][12][64][8] bf16
    const float* __restrict__ bias,      // [512]
    const float* __restrict__ gamma,     // [512]
    const float* __restrict__ beta,      // [512]
    const float* __restrict__ mask_tok,  // [512]
    const float* __restrict__ vis,       // [BT]
    float* __restrict__ out)             // [BT,512]
{
    const int tid    = threadIdx.x;
    const int ch     = tid >> 6;          // col-eighth 0..7 (4 n-tiles each)
    const int lane   = tid & 63;
    const int lane_m = lane & 15;
    const int lane_g = lane >> 4;
    const int mrow0  = blockIdx.x * 16;

    // preload the block's 12 A-fragments (16 rows x full K; same for all waves)
    bf16x8 afrag[KSTEPS];
    {
        const unsigned short* Arow = pooled_bf + (size_t)(mrow0 + lane_m) * D_BB + lane_g * 8;
#pragma unroll
        for (int ks = 0; ks < KSTEPS; ++ks)
            afrag[ks] = *(const bf16x8*)(Arow + ks * 32);
    }

    f32x4 acc[4];
#pragma unroll
    for (int nt = 0; nt < 4; ++nt) acc[nt] = (f32x4){0.f, 0.f, 0.f, 0.f};

    // fully-unrolled 4 x 12 = 48 loads + 48 MFMAs
#pragma unroll
    for (int nt = 0; nt < 4; ++nt) {
        const unsigned short* bp = wpack + ((size_t)((ch * 4 + nt) * KSTEPS) * 64 + lane) * 8;
#pragma unroll
        for (int ks = 0; ks < KSTEPS; ++ks) {
            const bf16x8 b = *(const bf16x8*)(bp + (size_t)ks * 64 * 8);
            acc[nt] = __builtin_amdgcn_mfma_f32_16x16x32_bf16(afrag[ks], b, acc[nt], 0, 0, 0);
        }
    }

    // ---- bias add + LN partials (row m = lane_g*4 + r, col = ch*64 + nt*16 + lane_m) ----
    float s[4] = {0.f, 0.f, 0.f, 0.f}, s2[4] = {0.f, 0.f, 0.f, 0.f};
#pragma unroll
    for (int nt = 0; nt < 4; ++nt) {
        const float bs = bias[ch * 64 + nt * 16 + lane_m];
#pragma unroll
        for (int r = 0; r < 4; ++r) {
            const float v = acc[nt][r] + bs;
            acc[nt][r] = v;
            s[r] += v; s2[r] += v * v;
        }
    }
    // butterfly over the 16 lanes of the lane-group (low 4 lane bits)
#pragma unroll
    for (int off = 1; off < 16; off <<= 1) {
#pragma unroll
        for (int r = 0; r < 4; ++r) {
            s[r]  += __shfl_xor(s[r],  off);
            s2[r] += __shfl_xor(s2[r], off);
        }
    }

    __shared__ float lns[8][16][2];   // [ch][m][{s,s2}], 1 KB
    if (lane_m == 0) {
#pragma unroll
        for (int r = 0; r < 4; ++r) {
            lns[ch][lane_g * 4 + r][0] = s[r];
            lns[ch][lane_g * 4 + r][1] = s2[r];
        }
    }
    __syncthreads();

    // ---- per-row stats + vis ----
    float mean4[4], rstd4[4], v4[4], iv4[4];
#pragma unroll
    for (int r = 0; r < 4; ++r) {
        const int m = lane_g * 4 + r;
        float S = 0.f, S2 = 0.f;
#pragma unroll
        for (int c = 0; c < 8; ++c) { S += lns[c][m][0]; S2 += lns[c][m][1]; }
        const float mean = S * (1.f / (float)D_MODEL);
        const float var  = S2 * (1.f / (float)D_MODEL) - mean * mean;
        mean4[r] = mean;
        rstd4[r] = rsqrtf(var + LN_EPS);
        const float v = vis[mrow0 + m];
        v4[r] = v; iv4[r] = 1.f - v;
    }

    // ---- normalize + blend + store ----
#pragma unroll
    for (int nt = 0; nt < 4; ++nt) {
        const int n = ch * 64 + nt * 16 + lane_m;
        const float gm  = gamma[n];
        const float bt_ = beta[n];
        const float mt  = mask_tok[n];
#pragma unroll
        for (int r = 0; r < 4; ++r) {
            const int row = mrow0 + lane_g * 4 + r;
            const float o = v4[r] * ((acc[nt][r] - mean4[r]) * rstd4[r] * gm + bt_) + iv4[r] * mt;
            out[(size_t)row * D_MODEL + n] = o;
        }
    }
}

extern "C" void kernel_launch(void* const* d_in, const int* in_sizes, int n_in,
                              void* d_out, int out_size, void* d_ws, size_t ws_size,
                              hipStream_t stream) {
    const float* patch  = (const float*)d_in[0];  // [2048,196,384]
    const float* bboxes = (const float*)d_in[1];  // [2048,4]
    const float* vis    = (const float*)d_in[2];  // [2048]
    // d_in[3] = B, d_in[4] = T (scalars, unused)
    const float* W      = (const float*)d_in[5];  // [384,512]
    const float* bias   = (const float*)d_in[6];  // [512]
    const float* gamma  = (const float*)d_in[7];  // [512]
    const float* beta   = (const float*)d_in[8];  // [512]
    const float* mtok   = (const float*)d_in[9];  // [1,512]

    unsigned short* pooled_bf = (unsigned short*)d_ws;                       // 1.5 MB
    unsigned short* wpack     = (unsigned short*)((char*)d_ws + (2u << 20)); // 0.4 MB
    float* out = (float*)d_out;

    pool_kernel<<<BT_TOTAL, 768, 0, stream>>>(patch, bboxes, W, pooled_bf, wpack);
    mfma_ln_kernel<<<BT_TOTAL / 16, 512, 0, stream>>>(
        pooled_bf, wpack, bias, gamma, beta, mtok, vis, out);
}